// Round 1
// baseline (888.421 us; speedup 1.0000x reference)
//
#include <hip/hip_runtime.h>

// DiffAttention fused pipeline for MI355X (gfx950).
// Stages: f32->bf16 casts -> lambda -> proj GEMM (+bias+RoPE+scatter, V transposed)
//         -> attention (2-pass no-max softmax, attn write + PV) -> groupnorm -> out GEMM.
// All MFMA: v_mfma_f32_16x16x32_bf16. C/D layout: col=lane&15, row=(lane>>4)*4+reg (m89/m91).
// A layout: A[m=lane&15][k=quad*8+j]; B layout: B[k=quad*8+j][n=lane&15] (K-contiguous both).

typedef short bf16x8 __attribute__((ext_vector_type(8)));
typedef float f32x4  __attribute__((ext_vector_type(4)));
typedef unsigned short u16;

#define SLEN 2048
#define HID  2048
#define NH   16
#define NKVH 8
#define HDQ  128
#define DV   256
#define QK_SCALE 0.08838834764831845f   // 128^-0.5
#define LAMB_INIT 0.2f

__device__ __forceinline__ u16 f2bf(float x) {
  unsigned int u = __float_as_uint(x);
  u = (u + 0x7fffu + ((u >> 16) & 1u)) >> 16;   // RNE
  return (u16)u;
}
__device__ __forceinline__ float bf2f(u16 h) {
  return __uint_as_float(((unsigned int)h) << 16);
}

// async global->LDS, 16B per lane. LDS dest must be lane-linear (m104/m108).
__device__ __forceinline__ void stage16(const void* g, void* l) {
  __builtin_amdgcn_global_load_lds((__attribute__((address_space(1))) void*)(void*)g,
                                   (__attribute__((address_space(3))) void*)l, 16, 0, 0);
}

// ---------------- conversion kernels ----------------
__global__ __launch_bounds__(256) void k_cvt(const float* __restrict__ src,
                                             u16* __restrict__ dst, int n) {
  int i = (blockIdx.x * 256 + threadIdx.x) * 4;
  if (i >= n) return;
  float4 v = *(const float4*)(src + i);
  *(ushort4*)(dst + i) = make_ushort4(f2bf(v.x), f2bf(v.y), f2bf(v.z), f2bf(v.w));
}

__global__ __launch_bounds__(64) void k_lam(const float* __restrict__ lq1, const float* __restrict__ lk1,
                                            const float* __restrict__ lq2, const float* __restrict__ lk2,
                                            float* __restrict__ lam) {
  int h = blockIdx.x, l = threadIdx.x;
  float s1 = lq1[h*HDQ + l]*lk1[h*HDQ + l] + lq1[h*HDQ + 64 + l]*lk1[h*HDQ + 64 + l];
  float s2 = lq2[h*HDQ + l]*lk2[h*HDQ + l] + lq2[h*HDQ + 64 + l]*lk2[h*HDQ + 64 + l];
#pragma unroll
  for (int o = 1; o < 64; o <<= 1) { s1 += __shfl_xor(s1, o); s2 += __shfl_xor(s2, o); }
  if (l == 0) lam[h] = __expf(s1) - __expf(s2) + LAMB_INIT;
}

// ---------------- shared 128x128 bf16 GEMM core (A,B both K-contiguous) ----------------
template<int KD>
__device__ __forceinline__ void gemm_core(const u16* __restrict__ A, const u16* __restrict__ B,
                                          int m0, int n0, u16* smem, f32x4 acc[4][4]) {
  u16* As = smem;
  u16* Bs = smem + 8192;
  const int tid = threadIdx.x;
  const int wave = tid >> 6, lane = tid & 63, quad = lane >> 4, l16 = lane & 15;
  const int r0 = (wave & 1) * 64, c0 = (wave >> 1) * 64;
  for (int kt = 0; kt < KD; kt += 64) {
#pragma unroll
    for (int i = 0; i < 4; ++i) {
      int li = i * 256 + tid;
      int row = li >> 3, ce = (li & 7) * 8;
      stage16(A + (size_t)(m0 + row) * KD + kt + ce, As + li * 8);
      stage16(B + (size_t)(n0 + row) * KD + kt + ce, Bs + li * 8);
    }
    __syncthreads();  // drains vmcnt for global_load_lds
#pragma unroll
    for (int ks = 0; ks < 2; ++ks) {
      bf16x8 a[4], b[4];
#pragma unroll
      for (int i = 0; i < 4; ++i) a[i] = *(const bf16x8*)(As + (r0 + i*16 + l16)*64 + ks*32 + quad*8);
#pragma unroll
      for (int j = 0; j < 4; ++j) b[j] = *(const bf16x8*)(Bs + (c0 + j*16 + l16)*64 + ks*32 + quad*8);
#pragma unroll
      for (int i = 0; i < 4; ++i)
#pragma unroll
        for (int j = 0; j < 4; ++j)
          acc[i][j] = __builtin_amdgcn_mfma_f32_16x16x32_bf16(a[i], b[j], acc[i][j], 0, 0, 0);
    }
    __syncthreads();
  }
}

// ---------------- projection GEMM + bias + RoPE + scatter ----------------
// Wcat rows: [Wq(2048) | Wk(1024) | Wqn(2048) | Wkn(1024) | Wv(2048)] -> N=8192
// grid (16 m-blocks, 64 n-blocks)
__global__ __launch_bounds__(256) void k_proj(const u16* __restrict__ Xb, const u16* __restrict__ Wcat,
    const float* __restrict__ bq, const float* __restrict__ bk, const float* __restrict__ bqn,
    const float* __restrict__ bkn, const float* __restrict__ bv,
    const float* __restrict__ cosg, const float* __restrict__ sing,
    u16* __restrict__ Qg, u16* __restrict__ Kg, u16* __restrict__ Qng, u16* __restrict__ Kng,
    u16* __restrict__ Vtg)
{
  __shared__ u16 smem[16384];  // 32KB: As/Bs during GEMM, then 128x128 bf16 tile
  const int m0 = blockIdx.x * 128;
  const int cb = blockIdx.y;
  const int tid = threadIdx.x;
  f32x4 acc[4][4];
  const f32x4 zf = {0.f, 0.f, 0.f, 0.f};
#pragma unroll
  for (int i = 0; i < 4; ++i)
#pragma unroll
    for (int j = 0; j < 4; ++j) acc[i][j] = zf;

  gemm_core<HID>(Xb, Wcat, m0, cb * 128, smem, acc);

  const int wave = tid >> 6, lane = tid & 63, quad = lane >> 4, l16 = lane & 15;
  const int r0 = (wave & 1) * 64, c0 = (wave >> 1) * 64;

  // segment bias
  const float* bptr; int cloc;
  if      (cb < 16) { bptr = bq;  cloc = cb * 128; }
  else if (cb < 24) { bptr = bk;  cloc = (cb - 16) * 128; }
  else if (cb < 40) { bptr = bqn; cloc = (cb - 24) * 128; }
  else if (cb < 48) { bptr = bkn; cloc = (cb - 40) * 128; }
  else              { bptr = bv;  cloc = (cb - 48) * 128; }
  float bias[4];
#pragma unroll
  for (int j = 0; j < 4; ++j) bias[j] = bptr[cloc + c0 + j*16 + l16];

  // acc -> bf16 tile in smem (C layout: row=quad*4+reg, col=l16)
#pragma unroll
  for (int i = 0; i < 4; ++i)
#pragma unroll
    for (int j = 0; j < 4; ++j)
#pragma unroll
      for (int reg = 0; reg < 4; ++reg)
        smem[(r0 + i*16 + quad*4 + reg) * 128 + c0 + j*16 + l16] = f2bf(acc[i][j][reg] + bias[j]);
  __syncthreads();

  if (cb < 48) {
    // RoPE segments. Tile cols == one full head (HD=128), partner is d^64.
    u16* outp; float sc;
    if      (cb < 16) { outp = Qg  + (size_t)cb        * SLEN * HDQ; sc = QK_SCALE; }
    else if (cb < 24) { outp = Kg  + (size_t)(cb - 16) * SLEN * HDQ; sc = 1.f; }
    else if (cb < 40) { outp = Qng + (size_t)(cb - 24) * SLEN * HDQ; sc = QK_SCALE; }
    else              { outp = Kng + (size_t)(cb - 40) * SLEN * HDQ; sc = 1.f; }
    const int r = tid >> 1;
    const int dh = (tid & 1) * 64;
    const int s = m0 + r;
    const float sgn = dh ? 1.f : -1.f;  // rot[d] = -x[d+64] (d<64), +x[d-64] (d>=64)
#pragma unroll
    for (int dc = 0; dc < 64; dc += 4) {
      const int d = dh + dc;
      float4 cv = *(const float4*)(cosg + (size_t)s * HDQ + d);
      float4 sv = *(const float4*)(sing + (size_t)s * HDQ + d);
      float cvals[4] = {cv.x, cv.y, cv.z, cv.w};
      float svals[4] = {sv.x, sv.y, sv.z, sv.w};
      u16 o[4];
#pragma unroll
      for (int t = 0; t < 4; ++t) {
        float x  = bf2f(smem[r * 128 + d + t]);
        float xr = bf2f(smem[r * 128 + ((d + t) ^ 64)]);
        o[t] = f2bf((x * cvals[t] + sgn * xr * svals[t]) * sc);
      }
      *(ushort4*)(outp + (size_t)s * HDQ + d) = make_ushort4(o[0], o[1], o[2], o[3]);
    }
  } else {
    // V segment: transpose to Vt[kvh*256 + dv][s]
    const int kvh = (cb - 48) >> 1;
    const int dvh = ((cb - 48) & 1) * 128;
    const int dvl = tid >> 1;
    const int sc0 = (tid & 1) * 64;
    u16* dst = Vtg + ((size_t)(kvh * DV + dvh + dvl)) * SLEN + m0 + sc0;
#pragma unroll
    for (int u8 = 0; u8 < 8; ++u8) {
      bf16x8 pack;
#pragma unroll
      for (int e = 0; e < 8; ++e) pack[e] = (short)smem[(sc0 + u8*8 + e) * 128 + dvl];
      *(bf16x8*)(dst + u8 * 8) = pack;
    }
  }
}

// ---------------- attention: 2-pass no-max softmax + attn write + PV ----------------
// grid = 512 blocks: h = bid&15, qb = bid>>4 (64 q rows each). K/Kn/Vt B-frags direct from global (L2/LLC resident).
__global__ __launch_bounds__(256) void k_attn(
    const u16* __restrict__ Qg, const u16* __restrict__ Kg,
    const u16* __restrict__ Qng, const u16* __restrict__ Kng,
    const u16* __restrict__ Vtg, const float* __restrict__ lam,
    float* __restrict__ attn_out, float* __restrict__ Obuf,
    float* __restrict__ gsum, float* __restrict__ gsumsq)
{
  __shared__ u16 Qs[64 * 136];   // +8 pad: breaks 16-way bank aliasing on A-frag reads
  __shared__ u16 Qns[64 * 136];
  __shared__ u16 Ps[64 * 72];    // P tile (bf16), 72-stride pad
  __shared__ float l1s[64], l2s[64];

  const int tid = threadIdx.x;
  const int h = blockIdx.x & 15, qb = blockIdx.x >> 4;
  const int q0 = qb * 64, kvh = h >> 1;
  const u16* Qsrc  = Qg  + ((size_t)h * SLEN + q0) * HDQ;
  const u16* Qnsrc = Qng + ((size_t)h * SLEN + q0) * HDQ;

  // manual padded staging (once per block)
#pragma unroll
  for (int i = 0; i < 4; ++i) {
    int li = i * 256 + tid;
    int row = li >> 4, col = (li & 15) * 8;
    *(bf16x8*)(Qs  + row * 136 + col) = *(const bf16x8*)(Qsrc  + li * 8);
    *(bf16x8*)(Qns + row * 136 + col) = *(const bf16x8*)(Qnsrc + li * 8);
  }
  if (tid < 64) { l1s[tid] = 0.f; l2s[tid] = 0.f; }
  __syncthreads();

  const int wave = tid >> 6, lane = tid & 63, quad = lane >> 4, l16 = lane & 15;
  const u16* Kb  = Kg  + (size_t)kvh * SLEN * HDQ;
  const u16* Knb = Kng + (size_t)kvh * SLEN * HDQ;
  const f32x4 zf = {0.f, 0.f, 0.f, 0.f};

#define COMPUTE_SSN(Sv, Snv)                                                              \
  {                                                                                       \
    _Pragma("unroll")                                                                     \
    for (int ks = 0; ks < 4; ++ks) {                                                      \
      const bf16x8 bk_  = *(const bf16x8*)(Kb  + (size_t)(cc0 + l16) * HDQ + ks*32 + quad*8); \
      const bf16x8 bkn_ = *(const bf16x8*)(Knb + (size_t)(cc0 + l16) * HDQ + ks*32 + quad*8); \
      _Pragma("unroll")                                                                   \
      for (int m = 0; m < 4; ++m) {                                                       \
        const bf16x8 aq_  = *(const bf16x8*)(Qs  + (m*16 + l16) * 136 + ks*32 + quad*8);  \
        const bf16x8 aqn_ = *(const bf16x8*)(Qns + (m*16 + l16) * 136 + ks*32 + quad*8);  \
        Sv[m]  = __builtin_amdgcn_mfma_f32_16x16x32_bf16(aq_,  bk_,  Sv[m], 0, 0, 0);     \
        Snv[m] = __builtin_amdgcn_mfma_f32_16x16x32_bf16(aqn_, bkn_, Snv[m], 0, 0, 0);    \
      }                                                                                   \
    }                                                                                     \
  }

  // ---- pass 1: row sums of exp(s), exp(sn). No max shift (|s| <= ~5, exp safe in fp32).
  float r1[4][4], r2[4][4];
#pragma unroll
  for (int m = 0; m < 4; ++m)
#pragma unroll
    for (int reg = 0; reg < 4; ++reg) { r1[m][reg] = 0.f; r2[m][reg] = 0.f; }

  for (int kb = 0; kb < 32; ++kb) {
    const int cc0 = kb * 64 + wave * 16;
    f32x4 S[4], Sn[4];
#pragma unroll
    for (int m = 0; m < 4; ++m) { S[m] = zf; Sn[m] = zf; }
    COMPUTE_SSN(S, Sn)
#pragma unroll
    for (int m = 0; m < 4; ++m)
#pragma unroll
      for (int reg = 0; reg < 4; ++reg) {
        r1[m][reg] += __expf(S[m][reg]);
        r2[m][reg] += __expf(Sn[m][reg]);
      }
  }
#pragma unroll
  for (int m = 0; m < 4; ++m)
#pragma unroll
    for (int reg = 0; reg < 4; ++reg) {
      float v1 = r1[m][reg], v2 = r2[m][reg];
#pragma unroll
      for (int o = 1; o < 16; o <<= 1) { v1 += __shfl_xor(v1, o); v2 += __shfl_xor(v2, o); }
      if (l16 == 0) {
        atomicAdd(&l1s[m*16 + quad*4 + reg], v1);
        atomicAdd(&l2s[m*16 + quad*4 + reg], v2);
      }
    }
  __syncthreads();

  const float lamh = lam[h];
  float inv1[4][4], inv2[4][4];
#pragma unroll
  for (int m = 0; m < 4; ++m)
#pragma unroll
    for (int reg = 0; reg < 4; ++reg) {
      int row = m*16 + quad*4 + reg;
      inv1[m][reg] = 1.f / l1s[row];
      inv2[m][reg] = lamh / l2s[row];
    }

  // ---- pass 2: recompute scores, write attn (fp32), PV accumulate
  f32x4 O[4][4];
#pragma unroll
  for (int m = 0; m < 4; ++m)
#pragma unroll
    for (int n = 0; n < 4; ++n) O[m][n] = zf;

  float* ab = attn_out + ((size_t)h * SLEN + q0) * SLEN;
  const u16* Vb = Vtg + (size_t)(kvh * DV + wave * 64) * SLEN;

  for (int kb = 0; kb < 32; ++kb) {
    const int cc0 = kb * 64 + wave * 16;
    f32x4 S[4], Sn[4];
#pragma unroll
    for (int m = 0; m < 4; ++m) { S[m] = zf; Sn[m] = zf; }
    COMPUTE_SSN(S, Sn)
#pragma unroll
    for (int m = 0; m < 4; ++m)
#pragma unroll
      for (int reg = 0; reg < 4; ++reg) {
        const int row = m*16 + quad*4 + reg;
        float p = __expf(S[m][reg]) * inv1[m][reg] - __expf(Sn[m][reg]) * inv2[m][reg];
        ab[(size_t)row * SLEN + cc0 + l16] = p;           // attn output (fp32)
        Ps[row * 72 + wave * 16 + l16] = f2bf(p);          // P for PV
      }
    __syncthreads();
#pragma unroll
    for (int ks = 0; ks < 2; ++ks) {
      bf16x8 a[4];
#pragma unroll
      for (int m = 0; m < 4; ++m) a[m] = *(const bf16x8*)(Ps + (m*16 + l16) * 72 + ks*32 + quad*8);
#pragma unroll
      for (int n = 0; n < 4; ++n) {
        const bf16x8 bv_ = *(const bf16x8*)(Vb + (size_t)(n*16 + l16) * SLEN + kb*64 + ks*32 + quad*8);
#pragma unroll
        for (int m = 0; m < 4; ++m)
          O[m][n] = __builtin_amdgcn_mfma_f32_16x16x32_bf16(a[m], bv_, O[m][n], 0, 0, 0);
      }
    }
    __syncthreads();  // before next iter overwrites Ps
  }

  // epilogue: O -> Obuf (fp32) + group stats (group = h*2 + (q>=1024))
  float lsum = 0.f, lsq = 0.f;
#pragma unroll
  for (int m = 0; m < 4; ++m)
#pragma unroll
    for (int n = 0; n < 4; ++n)
#pragma unroll
      for (int reg = 0; reg < 4; ++reg) {
        const int row = m*16 + quad*4 + reg;
        const int dv = wave*64 + n*16 + l16;
        float v = O[m][n][reg];
        Obuf[((size_t)h * SLEN + q0 + row) * DV + dv] = v;
        lsum += v; lsq += v * v;
      }
#pragma unroll
  for (int o = 1; o < 64; o <<= 1) { lsum += __shfl_xor(lsum, o); lsq += __shfl_xor(lsq, o); }
  if (lane == 0) {
    const int g = h * 2 + (q0 >> 10);
    atomicAdd(&gsum[g], lsum);
    atomicAdd(&gsumsq[g], lsq);
  }
#undef COMPUTE_SSN
}

// ---------------- groupnorm finalize + normalize ----------------
__global__ void k_gfin(const float* __restrict__ gsum, const float* __restrict__ gsumsq,
                       float* __restrict__ mus, float* __restrict__ rstds) {
  int g = threadIdx.x;
  if (g >= 32) return;
  const float N = 262144.f;  // 1024 q-rows * 256 dv
  float mu = gsum[g] / N;
  float var = gsumsq[g] / N - mu * mu;
  mus[g] = mu;
  rstds[g] = rsqrtf(var + 1e-5f);
}

// Obuf[h][q][dv] -> Y[q][h*256+dv] bf16, with (x-mu)*rstd*gamma[c]+beta[c], *0.8
// gamma index c = (q & 1023) >> 3 (from the reshape(32,128,2048) algebra).
__global__ __launch_bounds__(256) void k_norm(const float* __restrict__ Obuf,
    const float* __restrict__ mus, const float* __restrict__ rstds,
    const float* __restrict__ gamma, const float* __restrict__ beta,
    u16* __restrict__ Yb)
{
  const int e = (blockIdx.x * 256 + threadIdx.x) * 4;
  const int h = e >> 19;          // / (2048*256)
  const int rem = e & 524287;
  const int q = rem >> 8;
  const int d = rem & 255;
  const int g = h * 2 + (q >> 10);
  const int c = (q & 1023) >> 3;
  const float mu = mus[g], rs = rstds[g];
  const float gm = gamma[c], bt = beta[c];
  float4 v = *(const float4*)(Obuf + e);
  float vals[4] = {v.x, v.y, v.z, v.w};
  u16 o[4];
#pragma unroll
  for (int t = 0; t < 4; ++t) o[t] = f2bf(((vals[t] - mu) * rs * gm + bt) * 0.8f);
  *(ushort4*)(Yb + (size_t)q * 4096 + h * DV + d) = make_ushort4(o[0], o[1], o[2], o[3]);
}

// ---------------- output GEMM: out = Y(2048x4096) @ Wo^T(2048x4096) + bo ----------------
__global__ __launch_bounds__(256) void k_out(const u16* __restrict__ Yb, const u16* __restrict__ Wob,
                                             const float* __restrict__ bo, float* __restrict__ out)
{
  __shared__ u16 smem[16384];
  const int m0 = blockIdx.x * 128, n0 = blockIdx.y * 128;
  f32x4 acc[4][4];
  const f32x4 zf = {0.f, 0.f, 0.f, 0.f};
#pragma unroll
  for (int i = 0; i < 4; ++i)
#pragma unroll
    for (int j = 0; j < 4; ++j) acc[i][j] = zf;

  gemm_core<4096>(Yb, Wob, m0, n0, smem, acc);

  const int tid = threadIdx.x;
  const int wave = tid >> 6, lane = tid & 63, quad = lane >> 4, l16 = lane & 15;
  const int r0 = (wave & 1) * 64, c0 = (wave >> 1) * 64;
#pragma unroll
  for (int j = 0; j < 4; ++j) {
    const float b = bo[n0 + c0 + j*16 + l16];
#pragma unroll
    for (int i = 0; i < 4; ++i)
#pragma unroll
      for (int reg = 0; reg < 4; ++reg)
        out[(size_t)(m0 + r0 + i*16 + quad*4 + reg) * 2048 + n0 + c0 + j*16 + l16] =
            acc[i][j][reg] + b;
  }
}

// ---------------- host launch ----------------
extern "C" void kernel_launch(void* const* d_in, const int* in_sizes, int n_in,
                              void* d_out, int out_size, void* d_ws, size_t ws_size,
                              hipStream_t stream) {
  const float* X    = (const float*)d_in[0];
  const float* cosg = (const float*)d_in[1];
  const float* sing = (const float*)d_in[2];
  const float* Wq   = (const float*)d_in[3];
  const float* bq   = (const float*)d_in[4];
  const float* Wk   = (const float*)d_in[5];
  const float* bk   = (const float*)d_in[6];
  const float* Wqn  = (const float*)d_in[7];
  const float* bqn  = (const float*)d_in[8];
  const float* Wkn  = (const float*)d_in[9];
  const float* bkn  = (const float*)d_in[10];
  const float* Wv   = (const float*)d_in[11];
  const float* bv   = (const float*)d_in[12];
  const float* Wo   = (const float*)d_in[13];
  const float* bo   = (const float*)d_in[14];
  const float* lq1  = (const float*)d_in[15];
  const float* lk1  = (const float*)d_in[16];
  const float* lq2  = (const float*)d_in[17];
  const float* lk2  = (const float*)d_in[18];
  const float* gamma= (const float*)d_in[19];
  const float* beta = (const float*)d_in[20];

  float* out0 = (float*)d_out;                 // (1,2048,2048) fp32
  float* attn = out0 + 4194304;                // (1,16,2048,2048) fp32, 256 MB

  // Xb/Wcat scratch lives in the attn output region (consumed by k_proj before
  // k_attn overwrites attn). 40 MB of 256 MB.
  char* attnB = (char*)attn;
  u16* Xb   = (u16*)(attnB + 0);               // 8 MB
  u16* Wcat = (u16*)(attnB + 8388608);         // 32 MB

  char* ws = (char*)d_ws;                      // ~96 MB used
  u16* Wob   = (u16*)(ws + 0);                 // 16 MB
  u16* Qg    = (u16*)(ws + 16777216);          // 8 MB
  u16* Kgp   = (u16*)(ws + 25165824);          // 4 MB
  u16* Qng   = (u16*)(ws + 29360128);          // 8 MB
  u16* Kng   = (u16*)(ws + 37748736);          // 4 MB
  u16* Vtg   = (u16*)(ws + 41943040);          // 8 MB
  float* lam    = (float*)(ws + 50331648);
  float* gsum   = (float*)(ws + 50331776);
  float* gsumsq = (float*)(ws + 50331904);
  float* musv   = (float*)(ws + 50332032);
  float* rstds  = (float*)(ws + 50332160);
  float* Obuf   = (float*)(ws + 50332672);     // 32 MB fp32
  u16* Yb       = (u16*)(ws + 83887104);       // 16 MB

  hipMemsetAsync(gsum, 0, 64 * sizeof(float), stream);

  k_cvt<<<4096, 256, 0, stream>>>(X,   Xb,               4194304);
  k_cvt<<<4096, 256, 0, stream>>>(Wq,  Wcat,             4194304);
  k_cvt<<<2048, 256, 0, stream>>>(Wk,  Wcat + 4194304,   2097152);
  k_cvt<<<4096, 256, 0, stream>>>(Wqn, Wcat + 6291456,   4194304);
  k_cvt<<<2048, 256, 0, stream>>>(Wkn, Wcat + 10485760,  2097152);
  k_cvt<<<4096, 256, 0, stream>>>(Wv,  Wcat + 12582912,  4194304);
  k_cvt<<<8192, 256, 0, stream>>>(Wo,  Wob,              8388608);
  k_lam<<<16, 64, 0, stream>>>(lq1, lk1, lq2, lk2, lam);

  k_proj<<<dim3(16, 64), 256, 0, stream>>>(Xb, Wcat, bq, bk, bqn, bkn, bv,
                                           cosg, sing, Qg, Kgp, Qng, Kng, Vtg);

  k_attn<<<512, 256, 0, stream>>>(Qg, Kgp, Qng, Kng, Vtg, lam, attn, Obuf, gsum, gsumsq);

  k_gfin<<<1, 32, 0, stream>>>(gsum, gsumsq, musv, rstds);
  k_norm<<<8192, 256, 0, stream>>>(Obuf, musv, rstds, gamma, beta, Yb);
  k_out<<<dim3(16, 16), 256, 0, stream>>>(Yb, Wob, bo, out0);
}